// Round 14
// baseline (649.737 us; speedup 1.0000x reference)
//
#include <hip/hip_runtime.h>
#include <hip/hip_fp16.h>
#include <math.h>

#define IN_DIM 128
#define HD 256
#define EPSLN 1e-5f

typedef _Float16 half8 __attribute__((ext_vector_type(8)));
typedef float f32x4 __attribute__((ext_vector_type(4)));
typedef float f32x2 __attribute__((ext_vector_type(2)));

// ---------------- helpers ----------------
__device__ inline void store4(float* p, float4 o) { *(float4*)p = o; }
__device__ inline void store4(__half* p, float4 o) {
    union { uint2 u; __half2 h[2]; } s;
    s.h[0] = __floats2half2_rn(o.x, o.y);
    s.h[1] = __floats2half2_rn(o.z, o.w);
    *(uint2*)p = s.u;
}
__device__ inline uint2 f4_to_h4(float4 o) {
    union { uint2 u; __half2 h[2]; } s;
    s.h[0] = __floats2half2_rn(o.x, o.y);
    s.h[1] = __floats2half2_rn(o.z, o.w);
    return s.u;
}
__device__ inline float4 h4_to_f4(uint2 u) {
    union { unsigned int w; __half2 h; } a, b;
    a.w = u.x; b.w = u.y;
    float2 lo = __half22float2(a.h), hi = __half22float2(b.h);
    return make_float4(lo.x, lo.y, hi.x, hi.y);
}
// 4 floats -> 4 packed fp8 e4m3 (OCP, gfx950 HW cvt)
__device__ inline unsigned int f4_to_fp8x4(float a, float b, float c, float d) {
    int v = 0;
    v = __builtin_amdgcn_cvt_pk_fp8_f32(a, b, v, false);
    v = __builtin_amdgcn_cvt_pk_fp8_f32(c, d, v, true);
    return (unsigned int)v;
}
__device__ inline float4 fp8x4_to_f4(unsigned int u) {
    f32x2 lo = __builtin_amdgcn_cvt_pk_f32_fp8((int)u, false);
    f32x2 hi = __builtin_amdgcn_cvt_pk_f32_fp8((int)u, true);
    return make_float4(lo.x, lo.y, hi.x, hi.y);
}

__device__ inline void async_copy16(const __half* g, _Float16* l) {
    __builtin_amdgcn_global_load_lds(
        (const __attribute__((address_space(1))) void*)g,
        (__attribute__((address_space(3))) void*)l,
        16, 0, 0);
}

// LN + ELU on 4 floats
__device__ inline float4 ln_elu4(float4 v, float4 w, float4 b, float mean, float inv) {
    float4 o;
    o.x = fmaf((v.x - mean) * inv, w.x, b.x);
    o.y = fmaf((v.y - mean) * inv, w.y, b.y);
    o.z = fmaf((v.z - mean) * inv, w.z, b.z);
    o.w = fmaf((v.w - mean) * inv, w.w, b.w);
    o.x = o.x > 0.f ? o.x : expm1f(o.x);
    o.y = o.y > 0.f ? o.y : expm1f(o.y);
    o.z = o.z > 0.f ? o.z : expm1f(o.z);
    o.w = o.w > 0.f ? o.w : expm1f(o.w);
    return o;
}

// Packed output column mapping: q[0:256) | kv-interleaved[256:768) | skip[768:1024)
__device__ inline void unpermute_col(int n, int& sel, int& c) {
    if (n < 256) { sel = 0; c = n; }
    else if (n < 768) {
        int j = n - 256, chunk = j >> 3, w = j & 7;
        if (w < 4) { sel = 1; c = chunk * 4 + w; }
        else       { sel = 2; c = chunk * 4 + w - 4; }
    } else { sel = 3; c = n - 768; }
}

// ---------------- fused prep: pack x, pack weights/biases, count degrees + ranks ----
__global__ void prep_k(
    const float4* __restrict__ x, __half* __restrict__ xh, int total4,
    const int* __restrict__ dst, int* __restrict__ counts, int* __restrict__ rank, int E,
    const float* __restrict__ Wq1, const float* __restrict__ Wk1,
    const float* __restrict__ Wv1, const float* __restrict__ Ws1,
    const float* __restrict__ Wq2, const float* __restrict__ Wk2,
    const float* __restrict__ Wv2, const float* __restrict__ Ws2,
    const float* __restrict__ Wo,
    const float* __restrict__ bq1, const float* __restrict__ bk1,
    const float* __restrict__ bv1, const float* __restrict__ bs1,
    const float* __restrict__ bq2, const float* __restrict__ bk2,
    const float* __restrict__ bv2, const float* __restrict__ bs2,
    __half* __restrict__ Wc1, __half* __restrict__ Wc2, __half* __restrict__ Wot,
    float* __restrict__ bc1, float* __restrict__ bc2)
{
    int idx = blockIdx.x * 256 + threadIdx.x;
    if (idx < total4) store4(xh + (size_t)idx * 4, x[idx]);
    if (idx < E) rank[idx] = atomicAdd(&counts[dst[idx]], 1);   // rank within dst bucket
    if (idx < 131072) {
        int n = idx >> 7, k = idx & 127;
        int sel, c; unpermute_col(n, sel, c);
        const float* W = (sel == 0) ? Wq1 : (sel == 1) ? Wk1 : (sel == 2) ? Wv1 : Ws1;
        Wc1[idx] = __float2half(W[(size_t)k * 256 + c]);
    } else if (idx < 393216) {
        int j = idx - 131072;
        int n = j >> 8, k = j & 255;
        int sel, c; unpermute_col(n, sel, c);
        const float* W = (sel == 0) ? Wq2 : (sel == 1) ? Wk2 : (sel == 2) ? Wv2 : Ws2;
        Wc2[j] = __float2half(W[(size_t)k * 256 + c]);
    } else if (idx < 409600) {
        int j = idx - 393216;
        int n = j >> 8, k = j & 255;
        Wot[j] = __float2half(Wo[(size_t)k * 64 + n]);
    } else if (idx < 410624) {
        int n = idx - 409600;
        int sel, c; unpermute_col(n, sel, c);
        const float* b = (sel == 0) ? bq1 : (sel == 1) ? bk1 : (sel == 2) ? bv1 : bs1;
        bc1[n] = b[c];
    } else if (idx < 411648) {
        int n = idx - 410624;
        int sel, c; unpermute_col(n, sel, c);
        const float* b = (sel == 0) ? bq2 : (sel == 1) ? bk2 : (sel == 2) ? bv2 : bs2;
        bc2[n] = b[c];
    }
}

// ---------------- MFMA GEMM: C[M x Nc] = A'[M x K] @ Wt^T + bias (f16 out) --------------
// LN=true: A' = ELU(LN(A)) applied inline during A staging (register path + ds_write,
// same XOR-swizzled LDS slots as the async path -> MFMA read side unchanged).
#define BM 128
#define BN 128
#define BK 64
#define TROWB 272   // f16 out-tile row stride (bytes)

template <bool LN>
__global__ __launch_bounds__(256) void gemm_mfma(
    const __half* __restrict__ A, const __half* __restrict__ Wt,
    const float* __restrict__ bias, __half* __restrict__ C,
    unsigned char* __restrict__ kv8,
    const float4* __restrict__ lnw4, const float4* __restrict__ lnb4,
    const double* __restrict__ stats, double cnt,
    int M, int K, int Nc)
{
    __shared__ char smem[BM * TROWB];
    _Float16* As = (_Float16*)smem;
    _Float16* Bs = (_Float16*)(smem + 16384);

    int tid = threadIdx.x;
    int lane = tid & 63, w = tid >> 6;
    int wm = w >> 1, wn = w & 1;
    int quad = lane >> 4, l16 = lane & 15;
    int row0 = blockIdx.x * BM, col0 = blockIdx.y * BN;

    float mean = 0.f, inv = 0.f;
    if constexpr (LN) {
        double mu = stats[0] / cnt;
        double var = stats[1] / cnt - mu * mu;
        if (var < 0.0) var = 0.0;
        mean = (float)mu;
        inv = (float)(1.0 / (sqrt(var) + (double)EPSLN));
    }

    f32x4 acc[4][4];
#pragma unroll
    for (int i = 0; i < 4; i++)
#pragma unroll
        for (int j = 0; j < 4; j++) acc[i][j] = (f32x4){0.f, 0.f, 0.f, 0.f};

    int srow = lane >> 3;
    int schunk = lane & 7;

    for (int k0 = 0; k0 < K; k0 += BK) {
#pragma unroll
        for (int t = 0; t < 4; t++) {
            int r = w * 32 + t * 8 + srow;
            int gr = row0 + r; if (gr > M - 1) gr = M - 1;
            int gchunk = schunk ^ (r & 7);
            if constexpr (!LN) {
                async_copy16(&A[(size_t)gr * K + k0 + gchunk * 8], &As[(w * 32 + t * 8) * 64]);
            } else {
                uint4 raw = *(const uint4*)&A[(size_t)gr * K + k0 + gchunk * 8];
                int c4 = (k0 + gchunk * 8) >> 2;
                float4 lo = ln_elu4(h4_to_f4(make_uint2(raw.x, raw.y)), lnw4[c4], lnb4[c4], mean, inv);
                float4 hi = ln_elu4(h4_to_f4(make_uint2(raw.z, raw.w)), lnw4[c4 + 1], lnb4[c4 + 1], mean, inv);
                uint2 plo = f4_to_h4(lo), phi = f4_to_h4(hi);
                *(uint4*)&As[(w * 32 + t * 8) * 64 + lane * 8] = make_uint4(plo.x, plo.y, phi.x, phi.y);
            }
        }
#pragma unroll
        for (int t = 0; t < 4; t++) {
            int r = w * 32 + t * 8 + srow;
            int gc = col0 + r; if (gc > Nc - 1) gc = Nc - 1;
            int gchunk = schunk ^ (r & 7);
            async_copy16(&Wt[(size_t)gc * K + k0 + gchunk * 8], &Bs[(w * 32 + t * 8) * 64]);
        }
        __syncthreads();

#pragma unroll
        for (int ks = 0; ks < 2; ks++) {
            half8 af[4], bf[4];
#pragma unroll
            for (int i = 0; i < 4; i++) {
                int ra = wm * 64 + i * 16 + l16;
                af[i] = *(half8*)&As[ra * 64 + (((ks * 4 + quad) ^ (ra & 7)) * 8)];
                int rb = wn * 64 + i * 16 + l16;
                bf[i] = *(half8*)&Bs[rb * 64 + (((ks * 4 + quad) ^ (rb & 7)) * 8)];
            }
#pragma unroll
            for (int i = 0; i < 4; i++)
#pragma unroll
                for (int j = 0; j < 4; j++)
                    acc[i][j] = __builtin_amdgcn_mfma_f32_16x16x32_f16(af[i], bf[j], acc[i][j], 0, 0, 0);
        }
        __syncthreads();
    }

#pragma unroll
    for (int j = 0; j < 4; j++) {
        int tcol = wn * 64 + j * 16 + l16;
        float bb = (col0 + tcol < Nc) ? bias[col0 + tcol] : 0.f;
#pragma unroll
        for (int i = 0; i < 4; i++) {
#pragma unroll
            for (int r = 0; r < 4; r++) {
                int trow = wm * 64 + i * 16 + quad * 4 + r;
                ((__half*)(smem + trow * TROWB))[tcol] = __float2half(acc[i][j][r] + bb);
            }
        }
    }
    __syncthreads();
    bool iskv = (col0 >= 256) && (col0 < 768);
    int crow = tid >> 4, cchunk = tid & 15;
    for (int p = 0; p < 8; p++) {
        int trow = p * 16 + crow;
        int grow = row0 + trow;
        if (grow >= M) continue;
        uint4 val = *(uint4*)(smem + trow * TROWB + cchunk * 16);
        if (iskv) {
            float4 lo = h4_to_f4(make_uint2(val.x, val.y));
            float4 hi = h4_to_f4(make_uint2(val.z, val.w));
            uint2 o8;
            o8.x = f4_to_fp8x4(lo.x, lo.y, lo.z, lo.w);
            o8.y = f4_to_fp8x4(hi.x, hi.y, hi.z, hi.w);
            *(uint2*)&kv8[(size_t)grow * 512 + (col0 - 256) + cchunk * 8] = o8;
        } else {
            *(uint4*)&C[(size_t)grow * Nc + col0 + cchunk * 8] = val;
        }
    }
}

// ---------------- output GEMM: D[M x 64] = ELU(LN(A))[M x 256] @ Wot^T + bo (fp32) -----
__global__ __launch_bounds__(256) void gemm_out_k(
    const __half* __restrict__ A, const __half* __restrict__ Wot,
    const float* __restrict__ bias, float* __restrict__ D,
    const float4* __restrict__ lnw4, const float4* __restrict__ lnb4,
    const double* __restrict__ stats, double cnt, int M)
{
    __shared__ _Float16 As[128 * 64];   // 16 KB
    __shared__ _Float16 Bs[64 * 64];    // 8 KB
    int tid = threadIdx.x;
    int lane = tid & 63, w = tid >> 6;
    int quad = lane >> 4, l16 = lane & 15;
    int row0 = blockIdx.x * 128;
    const int K = 256;

    double mu = stats[0] / cnt;
    double var = stats[1] / cnt - mu * mu;
    if (var < 0.0) var = 0.0;
    float mean = (float)mu;
    float inv = (float)(1.0 / (sqrt(var) + (double)EPSLN));

    f32x4 acc[2][4];
#pragma unroll
    for (int i = 0; i < 2; i++)
#pragma unroll
        for (int j = 0; j < 4; j++) acc[i][j] = (f32x4){0.f, 0.f, 0.f, 0.f};

    int srow = lane >> 3;
    int schunk = lane & 7;

    for (int k0 = 0; k0 < K; k0 += BK) {
#pragma unroll
        for (int t = 0; t < 4; t++) {
            int r = w * 32 + t * 8 + srow;
            int gr = row0 + r; if (gr > M - 1) gr = M - 1;
            int gchunk = schunk ^ (r & 7);
            uint4 raw = *(const uint4*)&A[(size_t)gr * K + k0 + gchunk * 8];
            int c4 = (k0 + gchunk * 8) >> 2;
            float4 lo = ln_elu4(h4_to_f4(make_uint2(raw.x, raw.y)), lnw4[c4], lnb4[c4], mean, inv);
            float4 hi = ln_elu4(h4_to_f4(make_uint2(raw.z, raw.w)), lnw4[c4 + 1], lnb4[c4 + 1], mean, inv);
            uint2 plo = f4_to_h4(lo), phi = f4_to_h4(hi);
            *(uint4*)&As[(w * 32 + t * 8) * 64 + lane * 8] = make_uint4(plo.x, plo.y, phi.x, phi.y);
        }
#pragma unroll
        for (int t = 0; t < 2; t++) {
            int r = w * 16 + t * 8 + srow;     // 64 weight rows
            int gchunk = schunk ^ (r & 7);
            async_copy16(&Wot[(size_t)r * K + k0 + gchunk * 8], &Bs[(w * 16 + t * 8) * 64]);
        }
        __syncthreads();

#pragma unroll
        for (int ks = 0; ks < 2; ks++) {
            half8 af[2], bf[4];
#pragma unroll
            for (int i = 0; i < 2; i++) {
                int ra = w * 32 + i * 16 + l16;
                af[i] = *(half8*)&As[ra * 64 + (((ks * 4 + quad) ^ (ra & 7)) * 8)];
            }
#pragma unroll
            for (int j = 0; j < 4; j++) {
                int rb = j * 16 + l16;
                bf[j] = *(half8*)&Bs[rb * 64 + (((ks * 4 + quad) ^ (rb & 7)) * 8)];
            }
#pragma unroll
            for (int i = 0; i < 2; i++)
#pragma unroll
                for (int j = 0; j < 4; j++)
                    acc[i][j] = __builtin_amdgcn_mfma_f32_16x16x32_f16(af[i], bf[j], acc[i][j], 0, 0, 0);
        }
        __syncthreads();
    }

#pragma unroll
    for (int i = 0; i < 2; i++) {
#pragma unroll
        for (int j = 0; j < 4; j++) {
            int gcol = j * 16 + l16;
            float bb = bias[gcol];
#pragma unroll
            for (int r = 0; r < 4; r++) {
                int grow = row0 + w * 32 + i * 16 + quad * 4 + r;
                if (grow < M) D[(size_t)grow * 64 + gcol] = acc[i][j][r] + bb;
            }
        }
    }
}

// ---------------- edge bucketing ----------------
__global__ __launch_bounds__(1024) void scan_k(const int* __restrict__ counts,
                                               int* __restrict__ offs, int n)
{
    __shared__ int wsum[16];
    __shared__ int wpre[16];
    int tid = threadIdx.x, lane = tid & 63, wid = tid >> 6;
    int per = (n + 1023) / 1024;
    int start = tid * per, end = min(start + per, n);
    int sum = 0;
    for (int i = start; i < end; i++) sum += counts[i];
    int v = sum;
#pragma unroll
    for (int d = 1; d < 64; d <<= 1) {
        int t = __shfl_up(v, (unsigned)d, 64);
        if (lane >= d) v += t;
    }
    if (lane == 63) wsum[wid] = v;
    __syncthreads();
    if (tid == 0) {
        int acc = 0;
        for (int i = 0; i < 16; i++) { wpre[i] = acc; acc += wsum[i]; }
    }
    __syncthreads();
    int pre = wpre[wid] + v - sum;
    for (int i = start; i < end; i++) { offs[i] = pre; pre += counts[i]; }
    if (end == n && start <= n) offs[n] = pre;
}

// atomic-free: position = segment offset + precomputed rank
__global__ void scatter_k(const int* __restrict__ src, const int* __restrict__ dst,
                          const float* __restrict__ attr, const int* __restrict__ offs,
                          const int* __restrict__ rank, int2* __restrict__ edat, int E)
{
    int e = blockIdx.x * 256 + threadIdx.x;
    if (e < E) {
        int p = offs[dst[e]] + rank[e];
        edat[p] = make_int2(src[e], __float_as_int(attr[e]));
    }
}

// ---------------- attention: one wave per dst node, online softmax (R8 structure) ----
// 2048 persistent blocks: block lifetime >> epilogue keeps the miss pipeline full
// (R10 measured: 1 group/block -> 315 us vs 124 us; do not shrink block lifetime).
__global__ __launch_bounds__(256) void attn_k(
    const uint2* __restrict__ q2, const uint2* __restrict__ kv8u2,
    const float* __restrict__ We,
    __half* __restrict__ hwork, const int2* __restrict__ edat,
    const int* __restrict__ offs,
    double* __restrict__ stats, int n, int nGroups)
{
    int lane = threadIdx.x & 63;
    int wid = threadIdx.x >> 6;
    float4 we = ((const float4*)We)[lane];
    float tsum = 0.f, tsq = 0.f;

    for (int g = blockIdx.x; g < nGroups; g += gridDim.x) {
        int node = g * 4 + wid;
        if (node >= n) continue;
        float4 qv = h4_to_f4(q2[(size_t)node * 256 + lane]);
        float qwe = qv.x * we.x + qv.y * we.y + qv.z * we.z + qv.w * we.w;
        qwe += __shfl_xor(qwe, 1);
        qwe += __shfl_xor(qwe, 2);
        qwe += __shfl_xor(qwe, 4);

        float4 accv = make_float4(0.f, 0.f, 0.f, 0.f);
        float sat = 0.f;
        float m = -INFINITY, l = 0.f;
        int i0 = offs[node], i1 = offs[node + 1];

        auto proc = [&](uint2 kvraw, float at) {
            float4 kv = fp8x4_to_f4(kvraw.x);
            float p = qv.x * kv.x + qv.y * kv.y + qv.z * kv.z + qv.w * kv.w;
            p += __shfl_xor(p, 1);
            p += __shfl_xor(p, 2);
            p += __shfl_xor(p, 4);
            p = fmaf(at, qwe, p) * 0.17677669529663687f;   // (q.k + at*q.we)/sqrt(32)
            float mn = fmaxf(m, p);
            float corr = __expf(m - mn);
            float wgt = __expf(p - mn);
            l = l * corr + wgt;
            sat = fmaf(sat, corr, wgt * at);
            float4 vv = fp8x4_to_f4(kvraw.y);
            accv.x = fmaf(accv.x, corr, wgt * vv.x);
            accv.y = fmaf(accv.y, corr, wgt * vv.y);
            accv.z = fmaf(accv.z, corr, wgt * vv.z);
            accv.w = fmaf(accv.w, corr, wgt * vv.w);
            m = mn;
        };

        int i = i0;
        for (; i + 8 <= i1; i += 8) {
            int2 ed[8];
#pragma unroll
            for (int u = 0; u < 8; u++) ed[u] = edat[i + u];
            uint2 kvv[8];
#pragma unroll
            for (int u = 0; u < 8; u++)
                kvv[u] = kv8u2[(size_t)ed[u].x * 64 + lane];
#pragma unroll
            for (int u = 0; u < 8; u++) proc(kvv[u], __int_as_float(ed[u].y));
        }
        for (; i < i1; i++) {
            int2 ed = edat[i];
            uint2 kvraw = kv8u2[(size_t)ed.x * 64 + lane];
            proc(kvraw, __int_as_float(ed.y));
        }

        float inv = (l > 0.f) ? 1.f / l : 0.f;
        float4 sk = h4_to_f4(q2[(size_t)node * 256 + 192 + lane]);
        float sw = sat * inv;
        float4 o;
        o.x = fmaf(accv.x, inv, fmaf(sw, we.x, sk.x));
        o.y = fmaf(accv.y, inv, fmaf(sw, we.y, sk.y));
        o.z = fmaf(accv.z, inv, fmaf(sw, we.z, sk.z));
        o.w = fmaf(accv.w, inv, fmaf(sw, we.w, sk.w));
        store4(hwork + (size_t)node * 256 + lane * 4, o);
        tsum += o.x + o.y + o.z + o.w;
        tsq += o.x * o.x + o.y * o.y + o.z * o.z + o.w * o.w;
    }

#pragma unroll
    for (int d = 1; d < 64; d <<= 1) {
        tsum += __shfl_xor(tsum, d);
        tsq += __shfl_xor(tsq, d);
    }
    __shared__ float red[8];
    if (lane == 0) { red[wid] = tsum; red[4 + wid] = tsq; }
    __syncthreads();
    if (threadIdx.x == 0) {
        double s = (double)red[0] + (double)red[1] + (double)red[2] + (double)red[3];
        double sq = (double)red[4] + (double)red[5] + (double)red[6] + (double)red[7];
        atomicAdd(&stats[0], s);
        atomicAdd(&stats[1], sq);
    }
}

// ---------------- driver ----------------
extern "C" void kernel_launch(void* const* d_in, const int* in_sizes, int n_in,
                              void* d_out, int out_size, void* d_ws, size_t ws_size,
                              hipStream_t stream)
{
    const float* x      = (const float*)d_in[0];
    const int*   ei     = (const int*)d_in[1];
    const float* eattr  = (const float*)d_in[2];
    const float* Wq1 = (const float*)d_in[3];  const float* bq1 = (const float*)d_in[4];
    const float* Wk1 = (const float*)d_in[5];  const float* bk1 = (const float*)d_in[6];
    const float* Wv1 = (const float*)d_in[7];  const float* bv1 = (const float*)d_in[8];
    const float* We1 = (const float*)d_in[9];
    const float* Ws1 = (const float*)d_in[10]; const float* bs1 = (const float*)d_in[11];
    const float* lnw1 = (const float*)d_in[12]; const float* lnb1 = (const float*)d_in[13];
    const float* Wq2 = (const float*)d_in[14]; const float* bq2 = (const float*)d_in[15];
    const float* Wk2 = (const float*)d_in[16]; const float* bk2 = (const float*)d_in[17];
    const float* Wv2 = (const float*)d_in[18]; const float* bv2 = (const float*)d_in[19];
    const float* We2 = (const float*)d_in[20];
    const float* Ws2 = (const float*)d_in[21]; const float* bs2 = (const float*)d_in[22];
    const float* lnw2 = (const float*)d_in[23]; const float* lnb2 = (const float*)d_in[24];
    const float* Wo  = (const float*)d_in[25]; const float* bo  = (const float*)d_in[26];

    const int N = in_sizes[0] / IN_DIM;
    const int E = in_sizes[2];
    const int* esrc = ei;
    const int* edst = ei + E;

    char* ws = (char*)d_ws;
    size_t off = 0;
    auto alloc = [&](size_t bytes) -> char* {
        char* p = ws + off;
        off += (bytes + 255) / 256 * 256;
        return p;
    };
    int*    counts = (int*)alloc((size_t)N * 4);
    double* stats  = (double*)alloc(64);
    size_t zbytes = off;
    int*    rank   = (int*)alloc((size_t)E * 4);
    int*    offs   = (int*)alloc((size_t)(N + 1) * 4);
    int2*   edat   = (int2*)alloc((size_t)E * 8);
    __half* xh     = (__half*)alloc((size_t)N * IN_DIM * 2);
    __half* qkvs   = (__half*)alloc((size_t)N * 1024 * 2);
    unsigned char* kv8 = (unsigned char*)alloc((size_t)N * 512);
    __half* hwork  = (__half*)alloc((size_t)N * HD * 2);
    __half* Wc1    = (__half*)alloc((size_t)1024 * IN_DIM * 2);
    __half* Wc2    = (__half*)alloc((size_t)1024 * HD * 2);
    __half* Wot    = (__half*)alloc((size_t)64 * HD * 2);
    float*  bc1    = (float*)alloc(1024 * 4);
    float*  bc2    = (float*)alloc(1024 * 4);

    hipMemsetAsync(d_ws, 0, zbytes, stream);

    int total4x = N * (IN_DIM / 4);
    int prepWork = total4x > E ? total4x : E;
    if (prepWork < 411648) prepWork = 411648;
    prep_k<<<(prepWork + 255) / 256, 256, 0, stream>>>(
        (const float4*)x, xh, total4x, edst, counts, rank, E,
        Wq1, Wk1, Wv1, Ws1, Wq2, Wk2, Wv2, Ws2, Wo,
        bq1, bk1, bv1, bs1, bq2, bk2, bv2, bs2,
        Wc1, Wc2, Wot, bc1, bc2);

    scan_k<<<1, 1024, 0, stream>>>(counts, offs, N);
    scatter_k<<<(E + 255) / 256, 256, 0, stream>>>(esrc, edst, eattr, offs, rank,
                                                   edat, E);

    dim3 gqkvs((N + BM - 1) / BM, 1024 / BN);
    int nGroups = (N + 3) / 4;
    int gaBlocks = nGroups < 2048 ? nGroups : 2048;   // persistent blocks (proven R8 config)
    double cnt = (double)N * HD;
    dim3 gout((N + 127) / 128);

    // ---- layer 1 ----
    gemm_mfma<false><<<gqkvs, 256, 0, stream>>>(xh, Wc1, bc1, qkvs, kv8,
                                                nullptr, nullptr, nullptr, 0.0,
                                                N, IN_DIM, 1024);
    attn_k<<<gaBlocks, 256, 0, stream>>>((const uint2*)qkvs, (const uint2*)kv8, We1,
                                         hwork, edat, offs, stats, N, nGroups);

    // ---- layer 2 (LN1+ELU fused into A staging) ----
    gemm_mfma<true><<<gqkvs, 256, 0, stream>>>(hwork, Wc2, bc2, qkvs, kv8,
                                               (const float4*)lnw1, (const float4*)lnb1,
                                               stats, cnt,
                                               N, HD, 1024);
    attn_k<<<gaBlocks, 256, 0, stream>>>((const uint2*)qkvs, (const uint2*)kv8, We2,
                                         hwork, edat, offs, stats + 2, N, nGroups);

    // ---- output projection (LN2+ELU fused, fp32 out) ----
    gemm_out_k<<<gout, 256, 0, stream>>>(hwork, Wot, bo, (float*)d_out,
                                         (const float4*)lnw2, (const float4*)lnb2,
                                         stats + 2, cnt, N);
}

// Round 15
// 634.520 us; speedup vs baseline: 1.0240x; 1.0240x over previous
//
#include <hip/hip_runtime.h>
#include <hip/hip_fp16.h>
#include <math.h>

#define IN_DIM 128
#define HD 256
#define EPSLN 1e-5f

typedef _Float16 half8 __attribute__((ext_vector_type(8)));
typedef float f32x4 __attribute__((ext_vector_type(4)));
typedef float f32x2 __attribute__((ext_vector_type(2)));

// ---------------- helpers ----------------
__device__ inline void store4(float* p, float4 o) { *(float4*)p = o; }
__device__ inline void store4(__half* p, float4 o) {
    union { uint2 u; __half2 h[2]; } s;
    s.h[0] = __floats2half2_rn(o.x, o.y);
    s.h[1] = __floats2half2_rn(o.z, o.w);
    *(uint2*)p = s.u;
}
__device__ inline float4 h4_to_f4(uint2 u) {
    union { unsigned int w; __half2 h; } a, b;
    a.w = u.x; b.w = u.y;
    float2 lo = __half22float2(a.h), hi = __half22float2(b.h);
    return make_float4(lo.x, lo.y, hi.x, hi.y);
}
// 4 floats -> 4 packed fp8 e4m3 (OCP, gfx950 HW cvt)
__device__ inline unsigned int f4_to_fp8x4(float a, float b, float c, float d) {
    int v = 0;
    v = __builtin_amdgcn_cvt_pk_fp8_f32(a, b, v, false);
    v = __builtin_amdgcn_cvt_pk_fp8_f32(c, d, v, true);
    return (unsigned int)v;
}
__device__ inline float4 fp8x4_to_f4(unsigned int u) {
    f32x2 lo = __builtin_amdgcn_cvt_pk_f32_fp8((int)u, false);
    f32x2 hi = __builtin_amdgcn_cvt_pk_f32_fp8((int)u, true);
    return make_float4(lo.x, lo.y, hi.x, hi.y);
}

__device__ inline void async_copy16(const __half* g, _Float16* l) {
    __builtin_amdgcn_global_load_lds(
        (const __attribute__((address_space(1))) void*)g,
        (__attribute__((address_space(3))) void*)l,
        16, 0, 0);
}

// Packed output column mapping: q[0:256) | kv-interleaved[256:768) | skip[768:1024)
__device__ inline void unpermute_col(int n, int& sel, int& c) {
    if (n < 256) { sel = 0; c = n; }
    else if (n < 768) {
        int j = n - 256, chunk = j >> 3, w = j & 7;
        if (w < 4) { sel = 1; c = chunk * 4 + w; }
        else       { sel = 2; c = chunk * 4 + w - 4; }
    } else { sel = 3; c = n - 768; }
}

// ---------------- fused prep: pack x, pack weights/biases, count degrees + ranks ----
__global__ void prep_k(
    const float4* __restrict__ x, __half* __restrict__ xh, int total4,
    const int* __restrict__ dst, int* __restrict__ counts, int* __restrict__ rank, int E,
    const float* __restrict__ Wq1, const float* __restrict__ Wk1,
    const float* __restrict__ Wv1, const float* __restrict__ Ws1,
    const float* __restrict__ Wq2, const float* __restrict__ Wk2,
    const float* __restrict__ Wv2, const float* __restrict__ Ws2,
    const float* __restrict__ Wo,
    const float* __restrict__ bq1, const float* __restrict__ bk1,
    const float* __restrict__ bv1, const float* __restrict__ bs1,
    const float* __restrict__ bq2, const float* __restrict__ bk2,
    const float* __restrict__ bv2, const float* __restrict__ bs2,
    __half* __restrict__ Wc1, __half* __restrict__ Wc2, __half* __restrict__ Wot,
    float* __restrict__ bc1, float* __restrict__ bc2)
{
    int idx = blockIdx.x * 256 + threadIdx.x;
    if (idx < total4) store4(xh + (size_t)idx * 4, x[idx]);
    if (idx < E) rank[idx] = atomicAdd(&counts[dst[idx]], 1);   // rank within dst bucket
    if (idx < 131072) {
        int n = idx >> 7, k = idx & 127;
        int sel, c; unpermute_col(n, sel, c);
        const float* W = (sel == 0) ? Wq1 : (sel == 1) ? Wk1 : (sel == 2) ? Wv1 : Ws1;
        Wc1[idx] = __float2half(W[(size_t)k * 256 + c]);
    } else if (idx < 393216) {
        int j = idx - 131072;
        int n = j >> 8, k = j & 255;
        int sel, c; unpermute_col(n, sel, c);
        const float* W = (sel == 0) ? Wq2 : (sel == 1) ? Wk2 : (sel == 2) ? Wv2 : Ws2;
        Wc2[j] = __float2half(W[(size_t)k * 256 + c]);
    } else if (idx < 409600) {
        int j = idx - 393216;
        int n = j >> 8, k = j & 255;
        Wot[j] = __float2half(Wo[(size_t)k * 64 + n]);
    } else if (idx < 410624) {
        int n = idx - 409600;
        int sel, c; unpermute_col(n, sel, c);
        const float* b = (sel == 0) ? bq1 : (sel == 1) ? bk1 : (sel == 2) ? bv1 : bs1;
        bc1[n] = b[c];
    } else if (idx < 411648) {
        int n = idx - 410624;
        int sel, c; unpermute_col(n, sel, c);
        const float* b = (sel == 0) ? bq2 : (sel == 1) ? bk2 : (sel == 2) ? bv2 : bs2;
        bc2[n] = b[c];
    }
}

// ---------------- MFMA GEMM: C[M x Nc] = A[M x K] @ Wt^T + bias (f16 out) ----------------
#define BM 128
#define BN 128
#define BK 64
#define TROWB 272   // f16 out-tile row stride (bytes)

__global__ __launch_bounds__(256) void gemm_mfma(
    const __half* __restrict__ A, const __half* __restrict__ Wt,
    const float* __restrict__ bias, __half* __restrict__ C,
    unsigned char* __restrict__ kv8,
    int M, int K, int Nc)
{
    __shared__ char smem[BM * TROWB];
    _Float16* As = (_Float16*)smem;
    _Float16* Bs = (_Float16*)(smem + 16384);

    int tid = threadIdx.x;
    int lane = tid & 63, w = tid >> 6;
    int wm = w >> 1, wn = w & 1;
    int quad = lane >> 4, l16 = lane & 15;
    int row0 = blockIdx.x * BM, col0 = blockIdx.y * BN;

    f32x4 acc[4][4];
#pragma unroll
    for (int i = 0; i < 4; i++)
#pragma unroll
        for (int j = 0; j < 4; j++) acc[i][j] = (f32x4){0.f, 0.f, 0.f, 0.f};

    int srow = lane >> 3;
    int schunk = lane & 7;

    for (int k0 = 0; k0 < K; k0 += BK) {
#pragma unroll
        for (int t = 0; t < 4; t++) {
            int r = w * 32 + t * 8 + srow;
            int gr = row0 + r; if (gr > M - 1) gr = M - 1;
            int gchunk = schunk ^ (r & 7);
            async_copy16(&A[(size_t)gr * K + k0 + gchunk * 8], &As[(w * 32 + t * 8) * 64]);
        }
#pragma unroll
        for (int t = 0; t < 4; t++) {
            int r = w * 32 + t * 8 + srow;
            int gc = col0 + r; if (gc > Nc - 1) gc = Nc - 1;
            int gchunk = schunk ^ (r & 7);
            async_copy16(&Wt[(size_t)gc * K + k0 + gchunk * 8], &Bs[(w * 32 + t * 8) * 64]);
        }
        __syncthreads();

#pragma unroll
        for (int ks = 0; ks < 2; ks++) {
            half8 af[4], bf[4];
#pragma unroll
            for (int i = 0; i < 4; i++) {
                int ra = wm * 64 + i * 16 + l16;
                af[i] = *(half8*)&As[ra * 64 + (((ks * 4 + quad) ^ (ra & 7)) * 8)];
                int rb = wn * 64 + i * 16 + l16;
                bf[i] = *(half8*)&Bs[rb * 64 + (((ks * 4 + quad) ^ (rb & 7)) * 8)];
            }
#pragma unroll
            for (int i = 0; i < 4; i++)
#pragma unroll
                for (int j = 0; j < 4; j++)
                    acc[i][j] = __builtin_amdgcn_mfma_f32_16x16x32_f16(af[i], bf[j], acc[i][j], 0, 0, 0);
        }
        __syncthreads();
    }

#pragma unroll
    for (int j = 0; j < 4; j++) {
        int tcol = wn * 64 + j * 16 + l16;
        float bb = (col0 + tcol < Nc) ? bias[col0 + tcol] : 0.f;
#pragma unroll
        for (int i = 0; i < 4; i++) {
#pragma unroll
            for (int r = 0; r < 4; r++) {
                int trow = wm * 64 + i * 16 + quad * 4 + r;
                ((__half*)(smem + trow * TROWB))[tcol] = __float2half(acc[i][j][r] + bb);
            }
        }
    }
    __syncthreads();
    bool iskv = (col0 >= 256) && (col0 < 768);
    int crow = tid >> 4, cchunk = tid & 15;
    for (int p = 0; p < 8; p++) {
        int trow = p * 16 + crow;
        int grow = row0 + trow;
        if (grow >= M) continue;
        uint4 val = *(uint4*)(smem + trow * TROWB + cchunk * 16);
        if (iskv) {
            float4 lo = h4_to_f4(make_uint2(val.x, val.y));
            float4 hi = h4_to_f4(make_uint2(val.z, val.w));
            uint2 o8;
            o8.x = f4_to_fp8x4(lo.x, lo.y, lo.z, lo.w);
            o8.y = f4_to_fp8x4(hi.x, hi.y, hi.z, hi.w);
            *(uint2*)&kv8[(size_t)grow * 512 + (col0 - 256) + cchunk * 8] = o8;
        } else {
            *(uint4*)&C[(size_t)grow * Nc + col0 + cchunk * 8] = val;
        }
    }
}

// ---------------- output GEMM: D[M x 64] = A[M x 256] @ Wot^T + bo (fp32 out) ----------
__global__ __launch_bounds__(256) void gemm_out_k(
    const __half* __restrict__ A, const __half* __restrict__ Wot,
    const float* __restrict__ bias, float* __restrict__ D, int M)
{
    __shared__ _Float16 As[128 * 64];   // 16 KB
    __shared__ _Float16 Bs[64 * 64];    // 8 KB
    int tid = threadIdx.x;
    int lane = tid & 63, w = tid >> 6;
    int quad = lane >> 4, l16 = lane & 15;
    int row0 = blockIdx.x * 128;
    const int K = 256;

    f32x4 acc[2][4];
#pragma unroll
    for (int i = 0; i < 2; i++)
#pragma unroll
        for (int j = 0; j < 4; j++) acc[i][j] = (f32x4){0.f, 0.f, 0.f, 0.f};

    int srow = lane >> 3;
    int schunk = lane & 7;

    for (int k0 = 0; k0 < K; k0 += BK) {
#pragma unroll
        for (int t = 0; t < 4; t++) {
            int r = w * 32 + t * 8 + srow;
            int gr = row0 + r; if (gr > M - 1) gr = M - 1;
            int gchunk = schunk ^ (r & 7);
            async_copy16(&A[(size_t)gr * K + k0 + gchunk * 8], &As[(w * 32 + t * 8) * 64]);
        }
#pragma unroll
        for (int t = 0; t < 2; t++) {
            int r = w * 16 + t * 8 + srow;     // 64 weight rows
            int gchunk = schunk ^ (r & 7);
            async_copy16(&Wot[(size_t)r * K + k0 + gchunk * 8], &Bs[(w * 16 + t * 8) * 64]);
        }
        __syncthreads();

#pragma unroll
        for (int ks = 0; ks < 2; ks++) {
            half8 af[2], bf[4];
#pragma unroll
            for (int i = 0; i < 2; i++) {
                int ra = w * 32 + i * 16 + l16;
                af[i] = *(half8*)&As[ra * 64 + (((ks * 4 + quad) ^ (ra & 7)) * 8)];
            }
#pragma unroll
            for (int j = 0; j < 4; j++) {
                int rb = j * 16 + l16;
                bf[j] = *(half8*)&Bs[rb * 64 + (((ks * 4 + quad) ^ (rb & 7)) * 8)];
            }
#pragma unroll
            for (int i = 0; i < 2; i++)
#pragma unroll
                for (int j = 0; j < 4; j++)
                    acc[i][j] = __builtin_amdgcn_mfma_f32_16x16x32_f16(af[i], bf[j], acc[i][j], 0, 0, 0);
        }
        __syncthreads();
    }

#pragma unroll
    for (int i = 0; i < 2; i++) {
#pragma unroll
        for (int j = 0; j < 4; j++) {
            int gcol = j * 16 + l16;
            float bb = bias[gcol];
#pragma unroll
            for (int r = 0; r < 4; r++) {
                int grow = row0 + w * 32 + i * 16 + quad * 4 + r;
                if (grow < M) D[(size_t)grow * 64 + gcol] = acc[i][j][r] + bb;
            }
        }
    }
}

// ---------------- edge bucketing ----------------
__global__ __launch_bounds__(1024) void scan_k(const int* __restrict__ counts,
                                               int* __restrict__ offs, int n)
{
    __shared__ int wsum[16];
    __shared__ int wpre[16];
    int tid = threadIdx.x, lane = tid & 63, wid = tid >> 6;
    int per = (n + 1023) / 1024;
    int start = tid * per, end = min(start + per, n);
    int sum = 0;
    for (int i = start; i < end; i++) sum += counts[i];
    int v = sum;
#pragma unroll
    for (int d = 1; d < 64; d <<= 1) {
        int t = __shfl_up(v, (unsigned)d, 64);
        if (lane >= d) v += t;
    }
    if (lane == 63) wsum[wid] = v;
    __syncthreads();
    if (tid == 0) {
        int acc = 0;
        for (int i = 0; i < 16; i++) { wpre[i] = acc; acc += wsum[i]; }
    }
    __syncthreads();
    int pre = wpre[wid] + v - sum;
    for (int i = start; i < end; i++) { offs[i] = pre; pre += counts[i]; }
    if (end == n && start <= n) offs[n] = pre;
}

// atomic-free: position = segment offset + precomputed rank
__global__ void scatter_k(const int* __restrict__ src, const int* __restrict__ dst,
                          const float* __restrict__ attr, const int* __restrict__ offs,
                          const int* __restrict__ rank, int2* __restrict__ edat, int E)
{
    int e = blockIdx.x * 256 + threadIdx.x;
    if (e < E) {
        int p = offs[dst[e]] + rank[e];
        edat[p] = make_int2(src[e], __float_as_int(attr[e]));
    }
}

// ---------------- attention: one wave per dst node, online softmax (R8 structure) ----
// 2048 persistent blocks: block lifetime >> epilogue keeps the miss pipeline full
// (R10 measured: 1 group/block -> 315 us vs 124 us; do not shrink block lifetime).
__global__ __launch_bounds__(256) void attn_k(
    const uint2* __restrict__ q2, const uint2* __restrict__ kv8u2,
    const float* __restrict__ We,
    __half* __restrict__ hwork, const int2* __restrict__ edat,
    const int* __restrict__ offs,
    double* __restrict__ stats, int n, int nGroups)
{
    int lane = threadIdx.x & 63;
    int wid = threadIdx.x >> 6;
    float4 we = ((const float4*)We)[lane];
    float tsum = 0.f, tsq = 0.f;

    for (int g = blockIdx.x; g < nGroups; g += gridDim.x) {
        int node = g * 4 + wid;
        if (node >= n) continue;
        float4 qv = h4_to_f4(q2[(size_t)node * 256 + lane]);
        float qwe = qv.x * we.x + qv.y * we.y + qv.z * we.z + qv.w * we.w;
        qwe += __shfl_xor(qwe, 1);
        qwe += __shfl_xor(qwe, 2);
        qwe += __shfl_xor(qwe, 4);

        float4 accv = make_float4(0.f, 0.f, 0.f, 0.f);
        float sat = 0.f;
        float m = -INFINITY, l = 0.f;
        int i0 = offs[node], i1 = offs[node + 1];

        auto proc = [&](uint2 kvraw, float at) {
            float4 kv = fp8x4_to_f4(kvraw.x);
            float p = qv.x * kv.x + qv.y * kv.y + qv.z * kv.z + qv.w * kv.w;
            p += __shfl_xor(p, 1);
            p += __shfl_xor(p, 2);
            p += __shfl_xor(p, 4);
            p = fmaf(at, qwe, p) * 0.17677669529663687f;   // (q.k + at*q.we)/sqrt(32)
            float mn = fmaxf(m, p);
            float corr = __expf(m - mn);
            float wgt = __expf(p - mn);
            l = l * corr + wgt;
            sat = fmaf(sat, corr, wgt * at);
            float4 vv = fp8x4_to_f4(kvraw.y);
            accv.x = fmaf(accv.x, corr, wgt * vv.x);
            accv.y = fmaf(accv.y, corr, wgt * vv.y);
            accv.z = fmaf(accv.z, corr, wgt * vv.z);
            accv.w = fmaf(accv.w, corr, wgt * vv.w);
            m = mn;
        };

        int i = i0;
        for (; i + 8 <= i1; i += 8) {
            int2 ed[8];
#pragma unroll
            for (int u = 0; u < 8; u++) ed[u] = edat[i + u];
            uint2 kvv[8];
#pragma unroll
            for (int u = 0; u < 8; u++)
                kvv[u] = kv8u2[(size_t)ed[u].x * 64 + lane];
#pragma unroll
            for (int u = 0; u < 8; u++) proc(kvv[u], __int_as_float(ed[u].y));
        }
        for (; i < i1; i++) {
            int2 ed = edat[i];
            uint2 kvraw = kv8u2[(size_t)ed.x * 64 + lane];
            proc(kvraw, __int_as_float(ed.y));
        }

        float inv = (l > 0.f) ? 1.f / l : 0.f;
        float4 sk = h4_to_f4(q2[(size_t)node * 256 + 192 + lane]);
        float sw = sat * inv;
        float4 o;
        o.x = fmaf(accv.x, inv, fmaf(sw, we.x, sk.x));
        o.y = fmaf(accv.y, inv, fmaf(sw, we.y, sk.y));
        o.z = fmaf(accv.z, inv, fmaf(sw, we.z, sk.z));
        o.w = fmaf(accv.w, inv, fmaf(sw, we.w, sk.w));
        store4(hwork + (size_t)node * 256 + lane * 4, o);
        tsum += o.x + o.y + o.z + o.w;
        tsq += o.x * o.x + o.y * o.y + o.z * o.z + o.w * o.w;
    }

#pragma unroll
    for (int d = 1; d < 64; d <<= 1) {
        tsum += __shfl_xor(tsum, d);
        tsq += __shfl_xor(tsq, d);
    }
    __shared__ float red[8];
    if (lane == 0) { red[wid] = tsum; red[4 + wid] = tsq; }
    __syncthreads();
    if (threadIdx.x == 0) {
        double s = (double)red[0] + (double)red[1] + (double)red[2] + (double)red[3];
        double sq = (double)red[4] + (double)red[5] + (double)red[6] + (double)red[7];
        atomicAdd(&stats[0], s);
        atomicAdd(&stats[1], sq);
    }
}

// ---------------- LayerNorm apply (f16 in, f16 out; 4 elems/thread) ----------------
__global__ __launch_bounds__(256) void ln_apply(
    const uint2* __restrict__ in, __half* __restrict__ out,
    const float4* __restrict__ w4, const float4* __restrict__ b4,
    const double* __restrict__ stats, double cnt, int total4)
{
    int base = (blockIdx.x * 256 + threadIdx.x) * 4;
    if (base >= total4) return;
    double mu = stats[0] / cnt;
    double var = stats[1] / cnt - mu * mu;
    if (var < 0.0) var = 0.0;
    float mean = (float)mu;
    float inv = (float)(1.0 / (sqrt(var) + (double)EPSLN));
#pragma unroll
    for (int u = 0; u < 4; u++) {
        int i = base + u;
        if (i >= total4) return;
        int c = i & 63;
        float4 xv = h4_to_f4(in[i]);
        float4 w = w4[c], b = b4[c];
        float4 o;
        o.x = fmaf((xv.x - mean) * inv, w.x, b.x);
        o.y = fmaf((xv.y - mean) * inv, w.y, b.y);
        o.z = fmaf((xv.z - mean) * inv, w.z, b.z);
        o.w = fmaf((xv.w - mean) * inv, w.w, b.w);
        o.x = o.x > 0.f ? o.x : expm1f(o.x);
        o.y = o.y > 0.f ? o.y : expm1f(o.y);
        o.z = o.z > 0.f ? o.z : expm1f(o.z);
        o.w = o.w > 0.f ? o.w : expm1f(o.w);
        store4(out + (size_t)i * 4, o);
    }
}

// ---------------- driver ----------------
extern "C" void kernel_launch(void* const* d_in, const int* in_sizes, int n_in,
                              void* d_out, int out_size, void* d_ws, size_t ws_size,
                              hipStream_t stream)
{
    const float* x      = (const float*)d_in[0];
    const int*   ei     = (const int*)d_in[1];
    const float* eattr  = (const float*)d_in[2];
    const float* Wq1 = (const float*)d_in[3];  const float* bq1 = (const float*)d_in[4];
    const float* Wk1 = (const float*)d_in[5];  const float* bk1 = (const float*)d_in[6];
    const float* Wv1 = (const float*)d_in[7];  const float* bv1 = (const float*)d_in[8];
    const float* We1 = (const float*)d_in[9];
    const float* Ws1 = (const float*)d_in[10]; const float* bs1 = (const float*)d_in[11];
    const float* lnw1 = (const float*)d_in[12]; const float* lnb1 = (const float*)d_in[13];
    const float* Wq2 = (const float*)d_in[14]; const float* bq2 = (const float*)d_in[15];
    const float* Wk2 = (const float*)d_in[16]; const float* bk2 = (const float*)d_in[17];
    const float* Wv2 = (const float*)d_in[18]; const float* bv2 = (const float*)d_in[19];
    const float* We2 = (const float*)d_in[20];
    const float* Ws2 = (const float*)d_in[21]; const float* bs2 = (const float*)d_in[22];
    const float* lnw2 = (const float*)d_in[23]; const float* lnb2 = (const float*)d_in[24];
    const float* Wo  = (const float*)d_in[25]; const float* bo  = (const float*)d_in[26];

    const int N = in_sizes[0] / IN_DIM;
    const int E = in_sizes[2];
    const int* esrc = ei;
    const int* edst = ei + E;

    char* ws = (char*)d_ws;
    size_t off = 0;
    auto alloc = [&](size_t bytes) -> char* {
        char* p = ws + off;
        off += (bytes + 255) / 256 * 256;
        return p;
    };
    int*    counts = (int*)alloc((size_t)N * 4);
    double* stats  = (double*)alloc(64);
    size_t zbytes = off;
    int*    rank   = (int*)alloc((size_t)E * 4);
    int*    offs   = (int*)alloc((size_t)(N + 1) * 4);
    int2*   edat   = (int2*)alloc((size_t)E * 8);
    __half* xh     = (__half*)alloc((size_t)N * IN_DIM * 2);
    __half* qkvs   = (__half*)alloc((size_t)N * 1024 * 2);
    unsigned char* kv8 = (unsigned char*)alloc((size_t)N * 512);
    __half* hwork  = (__half*)alloc((size_t)N * HD * 2);
    __half* hio    = (__half*)alloc((size_t)N * HD * 2);
    __half* Wc1    = (__half*)alloc((size_t)1024 * IN_DIM * 2);
    __half* Wc2    = (__half*)alloc((size_t)1024 * HD * 2);
    __half* Wot    = (__half*)alloc((size_t)64 * HD * 2);
    float*  bc1    = (float*)alloc(1024 * 4);
    float*  bc2    = (float*)alloc(1024 * 4);

    hipMemsetAsync(d_ws, 0, zbytes, stream);

    int total4x = N * (IN_DIM / 4);
    int prepWork = total4x > E ? total4x : E;
    if (prepWork < 411648) prepWork = 411648;
    prep_k<<<(prepWork + 255) / 256, 256, 0, stream>>>(
        (const float4*)x, xh, total4x, edst, counts, rank, E,
        Wq1, Wk1, Wv1, Ws1, Wq2, Wk2, Wv2, Ws2, Wo,
        bq1, bk1, bv1, bs1, bq2, bk2, bv2, bs2,
        Wc1, Wc2, Wot, bc1, bc2);

    scan_k<<<1, 1024, 0, stream>>>(counts, offs, N);
    scatter_k<<<(E + 255) / 256, 256, 0, stream>>>(esrc, edst, eattr, offs, rank,
                                                   edat, E);

    dim3 gqkvs((N + BM - 1) / BM, 1024 / BN);
    int nGroups = (N + 3) / 4;
    int gaBlocks = nGroups < 2048 ? nGroups : 2048;   // persistent blocks (proven R8 config)
    int total4 = N * (HD / 4);
    dim3 gl((total4 / 4 + 255) / 256);
    dim3 gout((N + 127) / 128);

    // ---- layer 1 ----
    gemm_mfma<<<gqkvs, 256, 0, stream>>>(xh, Wc1, bc1, qkvs, kv8, N, IN_DIM, 1024);
    attn_k<<<gaBlocks, 256, 0, stream>>>((const uint2*)qkvs, (const uint2*)kv8, We1,
                                         hwork, edat, offs, stats, N, nGroups);
    ln_apply<<<gl, 256, 0, stream>>>((const uint2*)hwork, hio,
                                     (const float4*)lnw1, (const float4*)lnb1,
                                     stats, (double)N * HD, total4);

    // ---- layer 2 ----
    gemm_mfma<<<gqkvs, 256, 0, stream>>>(hio, Wc2, bc2, qkvs, kv8, N, HD, 1024);
    attn_k<<<gaBlocks, 256, 0, stream>>>((const uint2*)qkvs, (const uint2*)kv8, We2,
                                         hwork, edat, offs, stats + 2, N, nGroups);
    ln_apply<<<gl, 256, 0, stream>>>((const uint2*)hwork, hio,
                                     (const float4*)lnw2, (const float4*)lnb2,
                                     stats + 2, (double)N * HD, total4);

    // ---- output projection (fp32 out, dedicated 128x64 kernel) ----
    gemm_out_k<<<gout, 256, 0, stream>>>(hio, Wot, bo, (float*)d_out, N);
}